// Round 4
// baseline (911.162 us; speedup 1.0000x reference)
//
#include <hip/hip_runtime.h>
#include <hip/hip_bf16.h>
#include <stdint.h>

// Problem constants
#define DIM 384
#define KEY_DIM 32
#define HEADS 8
#define RES 14
#define NTOK 196
#define NH_KD 256
#define DD 128
#define DHF 1024
#define H_QKV 1536
#define BATCH 256
#define QSTR 224          // padded token stride (per-b), 16B-aligned
#define EPS_BN 1e-5f
#define LOG2E 1.4426950408889634f
#define QSCALE 0.25501860152f   // 32^-0.5 * log2(e)
#define PSTR 232          // LDS stride for V tile
#define OSTR 72           // LDS stride for per-wave O transpose tile

typedef unsigned short ushort_t;
typedef __attribute__((ext_vector_type(8))) short short8;
typedef __attribute__((ext_vector_type(4))) float floatx4;

__device__ __forceinline__ ushort_t f2bf(float f) {
  union { float f; unsigned int u; } v; v.f = f;
  unsigned int u = v.u;
  unsigned int r = (u + 0x7FFFu + ((u >> 16) & 1u)) >> 16;
  return (ushort_t)r;
}
__device__ __forceinline__ float bf2f(ushort_t h) {
  union { unsigned int u; float f; } v; v.u = ((unsigned int)h) << 16;
  return v.f;
}
__device__ __forceinline__ unsigned pk2bf(float lo, float hi) {
  __hip_bfloat162 h2 = __float22bfloat162_rn(make_float2(lo, hi));
  union { __hip_bfloat162 h; unsigned u; } c; c.h = h2; return c.u;
}
__device__ __forceinline__ void async_copy16(const ushort_t* g, ushort_t* l) {
  __builtin_amdgcn_global_load_lds((const __attribute__((address_space(1))) void*)g,
                                   (__attribute__((address_space(3))) void*)l, 16, 0, 0);
}

// ---------------- prep ----------------
// x (b, c, 196) fp32 -> xb (b, 224, c) bf16, pad rows 196..223 zeroed
__global__ void k_prep_x(const float* __restrict__ x, ushort_t* __restrict__ xb) {
  __shared__ float tile[64][65];
  const int b = blockIdx.y;
  const int c0 = blockIdx.x * 64;
  const int t = threadIdx.x;
  const int tr = t >> 6;
  const int tc = t & 63;
  for (int n0 = 0; n0 < QSTR; n0 += 64) {
    __syncthreads();
    #pragma unroll
    for (int k = 0; k < 16; ++k) {
      int r = k * 4 + tr;
      int n = n0 + tc;
      tile[r][tc] = (n < NTOK) ? x[((size_t)b * DIM + c0 + r) * NTOK + n] : 0.f;
    }
    __syncthreads();
    #pragma unroll
    for (int k = 0; k < 16; ++k) {
      int nl = k * 4 + tr;
      int n = n0 + nl;
      if (n < QSTR) xb[((size_t)b * QSTR + n) * DIM + c0 + tc] = f2bf(tile[tc][nl]);
    }
  }
}

__global__ void k_prep_w(const float* __restrict__ qkv_w, const float* __restrict__ proj_w,
                         ushort_t* __restrict__ wqkvb, ushort_t* __restrict__ wprojb) {
  int i = blockIdx.x * 256 + threadIdx.x;
  const int nA = H_QKV * DIM;
  const int nB = DIM * DHF;
  if (i < nA) wqkvb[i] = f2bf(qkv_w[i]);
  else if (i < nA + nB) wprojb[i - nA] = f2bf(proj_w[i - nA]);
}

// bias table in TRANSPOSED MFMA C-fragment layout (for S^T = K*Q^T):
// element (m = j*16 + quad*4 + r, n = rt*16 + l15); pre-scaled by log2e; -1e30 at m>=196.
__global__ void k_prep_abT(const float* __restrict__ biases, const int* __restrict__ idxs,
                           float* __restrict__ abgT) {
  int tid = blockIdx.x * 256 + threadIdx.x;
  if (tid >= HEADS * 13 * 13 * 64) return;
  const int l = tid & 63;
  int rem = tid >> 6;
  const int j = rem % 13; rem /= 13;
  const int rt = rem % 13;
  const int h = rem / 13;
  const int quad = l >> 4, l15 = l & 15;
  int n = rt * 16 + l15; if (n > NTOK - 1) n = NTOK - 1;
  #pragma unroll
  for (int r = 0; r < 4; ++r) {
    const int m = j * 16 + quad * 4 + r;
    float v = (m < NTOK) ? biases[h * NTOK + idxs[n * NTOK + m]] * LOG2E : -1e30f;
    abgT[(size_t)tid * 4 + r] = v;
  }
}

// ---------------- flat GEMM: C(M x cb*224) = A(M x K) * B(cb*224 x K)^T + BN ----------------
template<int KDIM, bool OUTF32>
__global__ __launch_bounds__(256, 2) void k_gemm(
    const ushort_t* __restrict__ A, const ushort_t* __restrict__ B,
    const float* __restrict__ bn_g, const float* __restrict__ bn_b,
    const float* __restrict__ bn_m, const float* __restrict__ bn_v,
    void* __restrict__ out) {
  __shared__ ushort_t sA[128 * 32];
  __shared__ ushort_t sB[128 * 32];
  const int n0 = blockIdx.x * 128;
  const int o0 = blockIdx.y * 128;
  const int t = threadIdx.x;
  const int w = t >> 6;
  const int l = t & 63;
  const int lr = l >> 2;
  const int ls = l & 3;
  const int arow0 = w * 32 + lr;
  const size_t aoff0 = (size_t)(o0 + arow0) * KDIM + ls * 8;
  const size_t aoff1 = aoff0 + (size_t)16 * KDIM;
  const size_t boff0 = (size_t)(n0 + arow0) * KDIM + ls * 8;
  const size_t boff1 = boff0 + (size_t)16 * KDIM;
  ushort_t* sA_w = sA + w * 1024;
  ushort_t* sB_w = sB + w * 1024;

  floatx4 acc[4][4];
  const floatx4 zero4 = {0.f, 0.f, 0.f, 0.f};
  #pragma unroll
  for (int i = 0; i < 4; ++i)
    #pragma unroll
    for (int j = 0; j < 4; ++j) acc[i][j] = zero4;

  const int wr = (w >> 1) * 64;
  const int wc = (w & 1) * 64;
  const int quad = l >> 4;
  const int l15 = l & 15;

  for (int kk = 0; kk < KDIM; kk += 32) {
    __syncthreads();
    async_copy16(A + aoff0 + kk, sA_w);
    async_copy16(A + aoff1 + kk, sA_w + 512);
    async_copy16(B + boff0 + kk, sB_w);
    async_copy16(B + boff1 + kk, sB_w + 512);
    __syncthreads();
    short8 af[4], bfv[4];
    #pragma unroll
    for (int i = 0; i < 4; ++i)
      af[i] = *(const short8*)(sA + (wr + i * 16 + l15) * 32 + quad * 8);
    #pragma unroll
    for (int j = 0; j < 4; ++j)
      bfv[j] = *(const short8*)(sB + (wc + j * 16 + l15) * 32 + quad * 8);
    #pragma unroll
    for (int i = 0; i < 4; ++i)
      #pragma unroll
      for (int j = 0; j < 4; ++j)
        acc[i][j] = __builtin_amdgcn_mfma_f32_16x16x32_bf16(af[i], bfv[j], acc[i][j], 0, 0, 0);
  }

  unsigned bq[4], nn[4];
  #pragma unroll
  for (int j = 0; j < 4; ++j) {
    const unsigned gn = n0 + wc + j * 16 + l15;
    bq[j] = gn / QSTR;
    nn[j] = gn - bq[j] * QSTR;
  }
  #pragma unroll
  for (int i = 0; i < 4; ++i) {
    #pragma unroll
    for (int r = 0; r < 4; ++r) {
      const int o = o0 + wr + i * 16 + quad * 4 + r;
      const float s = bn_g[o] * rsqrtf(bn_v[o] + EPS_BN);
      const float tt = bn_b[o] - bn_m[o] * s;
      #pragma unroll
      for (int j = 0; j < 4; ++j) {
        const float val = acc[i][j][r] * s + tt;
        if (OUTF32) {
          if (nn[j] < NTOK)
            ((float*)out)[((size_t)bq[j] * DIM + o) * NTOK + nn[j]] = val;
        } else {
          ((ushort_t*)out)[((size_t)bq[j] * H_QKV + o) * QSTR + nn[j]] = f2bf(val);
        }
      }
    }
  }
}

// ---------------- depthwise conv 3x3 + BN on q ; transpose q,k to (bh,n,32) ----------------
__global__ __launch_bounds__(128) void k_dwq(
    const ushort_t* __restrict__ qkvb, const float* __restrict__ dw_w,
    const float* __restrict__ dg, const float* __restrict__ db,
    const float* __restrict__ dm, const float* __restrict__ dv,
    ushort_t* __restrict__ qt, ushort_t* __restrict__ kt) {
  __shared__ ushort_t sq[32 * QSTR];
  __shared__ ushort_t sk[32 * QSTR];
  const int bh = blockIdx.x;
  const int b = bh >> 3, h = bh & 7;
  const int t = threadIdx.x;
  const int d = t & 31;
  const int grp = t >> 5;     // 0..3
  const int c = h * 32 + d;
  float wv[9];
  #pragma unroll
  for (int tp = 0; tp < 9; ++tp) wv[tp] = dw_w[c * 9 + tp];
  const float s = dg[c] * rsqrtf(dv[c] + EPS_BN);
  const float tt = db[c] - dm[c] * s;
  const uint4* gq = (const uint4*)(qkvb + ((size_t)b * H_QKV + h * 32) * QSTR);
  const uint4* gk = (const uint4*)(qkvb + ((size_t)b * H_QKV + NH_KD + h * 32) * QSTR);
  uint4* lq = (uint4*)sq;
  uint4* lk = (uint4*)sk;
  for (int i = t; i < 896; i += 128) { lq[i] = gq[i]; lk[i] = gk[i]; }
  __syncthreads();
  for (int i = 0; i < 49; ++i) {
    const int n = i * 4 + grp;
    const int y = n / 14, x = n - y * 14;
    float a = 0.f;
    #pragma unroll
    for (int dy = -1; dy <= 1; ++dy)
      #pragma unroll
      for (int dx = -1; dx <= 1; ++dx) {
        const int yy = y + dy, xx = x + dx;
        if (yy >= 0 && yy < 14 && xx >= 0 && xx < 14)
          a += bf2f(sq[d * QSTR + yy * 14 + xx]) * wv[(dy + 1) * 3 + (dx + 1)];
      }
    const float outv = (a * s + tt) * QSCALE;   // fold qk scale + log2e into q
    qt[((size_t)bh * NTOK + n) * 32 + d] = f2bf(outv);
    kt[((size_t)bh * NTOK + n) * 32 + d] = sk[d * QSTR + n];
  }
}

// ---------------- fused attention, d-split: 2 blocks per (b,h), 64 V-channels each ------
// 256 thr, LDS = sV 64x232 + sO 4x16x72 = 38912 B -> 4 blocks/CU at <=128 VGPR.
// S^T = K*Q^T (bias as C-init, no max-sub), softmax in-register, P exchanged to
// A-frag layout via ds_bpermute shuffles, O^T = V*P^T, post-normalized.
__global__ __launch_bounds__(256, 4) void k_attn(
    const ushort_t* __restrict__ qt, const ushort_t* __restrict__ kt,
    const ushort_t* __restrict__ qkvb, const float* __restrict__ abgT,
    ushort_t* __restrict__ rbuf) {
  __shared__ ushort_t sV[64 * PSTR];
  __shared__ ushort_t sO[4 * 16 * OSTR];
  const int id = blockIdx.x;
  const int dhalf = id & 1;
  const int bh = id >> 1;
  const int b = bh >> 3, h = bh & 7;
  const int t = threadIdx.x;
  const int w = t >> 6, l = t & 63;
  const int quad = l >> 4, l15 = l & 15;

  // stage V half: 64 rows x 224 cols (qkvb pad cols are finite BN-bias values;
  // they're multiplied by P=0 for m>=196, so no zeroing needed)
  {
    const ushort_t* vsrc = qkvb + ((size_t)b * H_QKV + 2 * NH_KD + h * DD + dhalf * 64) * QSTR;
    for (int i = t; i < 1792; i += 256) {
      const int row = i / 28, col = i - row * 28;
      *(uint4*)(sV + row * PSTR + col * 8) = *(const uint4*)(vsrc + (size_t)row * QSTR + col * 8);
    }
  }
  // K fragments -> registers (A-operand rows m): kf[j] = K[j*16+l15][quad*8..+7]
  short8 kf[13];
  const ushort_t* kbase = kt + (size_t)bh * NTOK * 32;
  #pragma unroll
  for (int j = 0; j < 13; ++j) {
    int krow = j * 16 + l15; if (krow > NTOK - 1) krow = NTOK - 1;
    kf[j] = *(const short8*)(kbase + krow * 32 + quad * 8);
  }
  __syncthreads();

  const ushort_t* qbase = qt + (size_t)bh * NTOK * 32;
  ushort_t* sOw = sO + w * 16 * OSTR;
  const floatx4 zero4 = {0.f, 0.f, 0.f, 0.f};
  const int srcA = ((l & 16) << 1) + l15;   // 32*(quad&1) + l15
  const int srcB = srcA + 16;
  const int tsel = l >> 5;                  // quad>>1

  for (int rt = w; rt < 13; rt += 4) {
    // ---- S^T tile: rows m (13 j-tiles), cols n = rt*16+l15. Bias as C-init.
    int qrow = rt * 16 + l15; if (qrow > NTOK - 1) qrow = NTOK - 1;
    const short8 aq = *(const short8*)(qbase + qrow * 32 + quad * 8);
    const floatx4* cbT = (const floatx4*)(abgT) + ((size_t)(h * 13 + rt) * 13) * 64 + l;
    floatx4 lg[13];
    #pragma unroll
    for (int j = 0; j < 13; ++j)
      lg[j] = __builtin_amdgcn_mfma_f32_16x16x32_bf16(kf[j], aq, cbT[j * 64], 0, 0, 0);

    // ---- exp2 (no max-sub; logits are O(1)) + sum over m (in-lane + 2 shuffles)
    float s0 = 0.f, s1 = 0.f, s2 = 0.f, s3 = 0.f;
    #pragma unroll
    for (int j = 0; j < 13; ++j) {
      lg[j][0] = exp2f(lg[j][0]); s0 += lg[j][0];
      lg[j][1] = exp2f(lg[j][1]); s1 += lg[j][1];
      lg[j][2] = exp2f(lg[j][2]); s2 += lg[j][2];
      lg[j][3] = exp2f(lg[j][3]); s3 += lg[j][3];
    }
    float ssum = (s0 + s1) + (s2 + s3);
    ssum += __shfl_xor(ssum, 16, 64);
    ssum += __shfl_xor(ssum, 32, 64);
    const float inv = 1.f / ssum;           // per n = l15, all lanes

    // ---- pack unnormalized P to bf16 pairs: plo[j] = (m+0,m+1), phi[j] = (m+2,m+3)
    unsigned plo[14], phi[14];
    #pragma unroll
    for (int j = 0; j < 13; ++j) {
      plo[j] = pk2bf(lg[j][0], lg[j][1]);
      phi[j] = pk2bf(lg[j][2], lg[j][3]);
    }
    plo[13] = 0; phi[13] = 0;               // m 208..223 -> P = 0

    // ---- AV: O^T = V * P^T. Per 32-m chunk: build P A-frag via 8 bpermutes.
    floatx4 acc[4];
    #pragma unroll
    for (int ct = 0; ct < 4; ++ct) acc[ct] = zero4;
    #pragma unroll
    for (int ks = 0; ks < 7; ++ks) {
      const unsigned a0 = __shfl((int)plo[2 * ks], srcA, 64);
      const unsigned a1 = __shfl((int)phi[2 * ks], srcA, 64);
      const unsigned a2 = __shfl((int)plo[2 * ks], srcB, 64);
      const unsigned a3 = __shfl((int)phi[2 * ks], srcB, 64);
      const unsigned b0 = __shfl((int)plo[2 * ks + 1], srcA, 64);
      const unsigned b1 = __shfl((int)phi[2 * ks + 1], srcA, 64);
      const unsigned b2 = __shfl((int)plo[2 * ks + 1], srcB, 64);
      const unsigned b3 = __shfl((int)phi[2 * ks + 1], srcB, 64);
      union { unsigned u[4]; short8 s; } pf;
      pf.u[0] = tsel ? b0 : a0;
      pf.u[1] = tsel ? b1 : a1;
      pf.u[2] = tsel ? b2 : a2;
      pf.u[3] = tsel ? b3 : a3;
      #pragma unroll
      for (int ct = 0; ct < 4; ++ct) {
        const short8 bv = *(const short8*)(sV + (ct * 16 + l15) * PSTR + ks * 32 + quad * 8);
        acc[ct] = __builtin_amdgcn_mfma_f32_16x16x32_bf16(bv, pf.s, acc[ct], 0, 0, 0);
      }
    }

    // ---- normalize + ReLU + pack along d into per-wave sO (O^T: row d, col n=l15)
    #pragma unroll
    for (int ct = 0; ct < 4; ++ct) {
      const float o0 = fmaxf(acc[ct][0] * inv, 0.f);
      const float o1 = fmaxf(acc[ct][1] * inv, 0.f);
      const float o2 = fmaxf(acc[ct][2] * inv, 0.f);
      const float o3 = fmaxf(acc[ct][3] * inv, 0.f);
      *(unsigned*)(sOw + l15 * OSTR + ct * 16 + quad * 4)     = pk2bf(o0, o1);
      *(unsigned*)(sOw + l15 * OSTR + ct * 16 + quad * 4 + 2) = pk2bf(o2, o3);
    }
    // ---- wide coalesced stores: 2 x uint4 per lane
    #pragma unroll
    for (int p = 0; p < 2; ++p) {
      const int i = l + p * 64;
      const int row = i >> 3;       // n-local 0..15
      const int col = i & 7;        // 8-elem chunk along d
      const int n = rt * 16 + row;
      const uint4 val = *(const uint4*)(sOw + row * OSTR + col * 8);
      if (n < NTOK)
        *(uint4*)(rbuf + ((size_t)b * QSTR + n) * DHF + h * DD + dhalf * 64 + col * 8) = val;
    }
  }
}

// ---------------- launch ----------------
extern "C" void kernel_launch(void* const* d_in, const int* in_sizes, int n_in,
                              void* d_out, int out_size, void* d_ws, size_t ws_size,
                              hipStream_t stream) {
  const float* x      = (const float*)d_in[0];
  const float* qkv_w  = (const float*)d_in[1];
  const float* qkv_g  = (const float*)d_in[2];
  const float* qkv_b  = (const float*)d_in[3];
  const float* qkv_m  = (const float*)d_in[4];
  const float* qkv_v  = (const float*)d_in[5];
  const float* dw_w   = (const float*)d_in[6];
  const float* dw_g   = (const float*)d_in[7];
  const float* dw_b   = (const float*)d_in[8];
  const float* dw_m   = (const float*)d_in[9];
  const float* dw_v   = (const float*)d_in[10];
  const float* proj_w = (const float*)d_in[11];
  const float* proj_g = (const float*)d_in[12];
  const float* proj_b = (const float*)d_in[13];
  const float* proj_m = (const float*)d_in[14];
  const float* proj_v = (const float*)d_in[15];
  const float* ab     = (const float*)d_in[16];
  const int*   idxs   = (const int*)d_in[17];
  (void)in_sizes; (void)n_in; (void)out_size;

  char* p = (char*)d_ws;
  ushort_t* wqkvb  = (ushort_t*)p; p += (size_t)H_QKV * DIM * 2;
  ushort_t* wprojb = (ushort_t*)p; p += (size_t)DIM * DHF * 2;
  float*    abgT   = (float*)p;    p += (size_t)HEADS * 13 * 13 * 64 * 4 * 4;
  const size_t fixed = (size_t)(p - (char*)d_ws);
  const size_t perb = (size_t)QSTR * DIM * 2 + (size_t)H_QKV * QSTR * 2
                    + 2 * (size_t)HEADS * NTOK * 32 * 2 + (size_t)QSTR * DHF * 2;
  int cb = 8;
  const int cands[6] = {256, 128, 64, 32, 16, 8};
  for (int i = 0; i < 6; ++i) {
    if (fixed + (size_t)cands[i] * perb <= ws_size) { cb = cands[i]; break; }
  }
  ushort_t* xb   = (ushort_t*)p;
  ushort_t* qkvb = xb + (size_t)cb * QSTR * DIM;
  ushort_t* qt   = qkvb + (size_t)cb * H_QKV * QSTR;
  ushort_t* kt   = qt + (size_t)cb * HEADS * NTOK * 32;
  ushort_t* rbuf = kt + (size_t)cb * HEADS * NTOK * 32;

  k_prep_w<<<(H_QKV * DIM + DIM * DHF + 255) / 256, 256, 0, stream>>>(qkv_w, proj_w, wqkvb, wprojb);
  k_prep_abT<<<(HEADS * 13 * 13 * 64 + 255) / 256, 256, 0, stream>>>(ab, idxs, abgT);

  const int NT = cb * QSTR / 128;
  for (int b0 = 0; b0 < BATCH; b0 += cb) {
    k_prep_x<<<dim3(6, cb), 256, 0, stream>>>(x + (size_t)b0 * DIM * NTOK, xb);
    k_gemm<DIM, false><<<dim3(NT, 12), 256, 0, stream>>>(wqkvb, xb, qkv_g, qkv_b, qkv_m, qkv_v, qkvb);
    k_dwq<<<cb * HEADS, 128, 0, stream>>>(qkvb, dw_w, dw_g, dw_b, dw_m, dw_v, qt, kt);
    k_attn<<<cb * HEADS * 2, 256, 0, stream>>>(qt, kt, qkvb, abgT, rbuf);
    k_gemm<DHF, true><<<dim3(NT, 3), 256, 0, stream>>>(wprojb, rbuf, proj_g, proj_b, proj_m, proj_v,
                                                       (float*)d_out + (size_t)b0 * DIM * NTOK);
  }
}